// Round 3
// baseline (87.664 us; speedup 1.0000x reference)
//
#include <hip/hip_runtime.h>
#include <math.h>

#define NROWS 32768
#define DIM   64
#define NCODE 4096
#define EPS_RMS 1.1920929e-07f
#define EPS_BN  1e-5f

typedef _Float16 f16x8 __attribute__((ext_vector_type(8)));
typedef float    f32x4 __attribute__((ext_vector_type(4)));

// ws byte layout
#define WS_PS   0                        // partial sums   [64][64] f32
#define WS_PQ   16384                    // partial sumsq  [64][64] f32
#define WS_CC   32768                    // ccn[4096] = -0.5*sum(c^2)
#define WS_CB32 49152                    // cb fp32 [4096][64]
#define WS_CH   (49152 + 1048576)        // cb f16 hi [4096][64]
#define WS_CL   (WS_CH + 524288)         // cb f16 lo [4096][64]

// out float offsets
#define OUT1 ((size_t)NROWS * DIM)           // z_e
#define OUT2 ((size_t)2 * NROWS * DIM)       // q
#define OUT3 (OUT2 + NROWS)                  // z_q

#define MFMA16(a, b, c) __builtin_amdgcn_mfma_f32_16x16x32_f16(a, b, c, 0, 0, 0)

__device__ __forceinline__ void async_copy16(void* lds, const void* g) {
    __builtin_amdgcn_global_load_lds(
        (const __attribute__((address_space(1))) unsigned int*)g,
        (__attribute__((address_space(3))) unsigned int*)lds, 16, 0, 0);
}

__global__ __launch_bounds__(256) void k_bn1(const float* __restrict__ w,
                                             char* __restrict__ wsb) {
    __shared__ float s1[4][64], s2[4][64];
    int lane = threadIdx.x & 63, v = threadIdx.x >> 6;
    long base = (long)blockIdx.x * 64 + v * 16;
    float s = 0.f, sq = 0.f;
    #pragma unroll
    for (int i = 0; i < 16; i++) {
        float x = w[(base + i) * DIM + lane];
        s += x; sq += x * x;
    }
    s1[v][lane] = s; s2[v][lane] = sq;
    __syncthreads();
    if (threadIdx.x < 64) {
        float ts = s1[0][lane] + s1[1][lane] + s1[2][lane] + s1[3][lane];
        float tq = s2[0][lane] + s2[1][lane] + s2[2][lane] + s2[3][lane];
        ((float*)(wsb + WS_PS))[blockIdx.x * 64 + lane] = ts;
        ((float*)(wsb + WS_PQ))[blockIdx.x * 64 + lane] = tq;
    }
}

__global__ __launch_bounds__(256) void k_cb(const float* __restrict__ w,
                                            const float* __restrict__ bnw,
                                            const float* __restrict__ bnb,
                                            char* __restrict__ wsb) {
    __shared__ float s1[4][64], s2[4][64], af[64], bf[64];
    int t = threadIdx.x, lane = t & 63, v = t >> 6;
    const float* ps = (const float*)(wsb + WS_PS);
    const float* pq = (const float*)(wsb + WS_PQ);
    float s = 0.f, sq = 0.f;
    #pragma unroll
    for (int b = 0; b < 16; b++) {
        s  += ps[(v * 16 + b) * 64 + lane];
        sq += pq[(v * 16 + b) * 64 + lane];
    }
    s1[v][lane] = s; s2[v][lane] = sq;
    __syncthreads();
    if (t < 64) {
        float ts = s1[0][lane] + s1[1][lane] + s1[2][lane] + s1[3][lane];
        float tq = s2[0][lane] + s2[1][lane] + s2[2][lane] + s2[3][lane];
        float mean = ts * (1.0f / NCODE);
        float var  = tq * (1.0f / NCODE) - mean * mean;
        float a = rsqrtf(var + EPS_BN) * bnw[lane];
        af[lane] = a;
        bf[lane] = bnb[lane] - mean * a;
    }
    __syncthreads();
    float a = af[lane], bb = bf[lane];
    float*     cb32 = (float*)(wsb + WS_CB32);
    _Float16*  chG  = (_Float16*)(wsb + WS_CH);
    _Float16*  clG  = (_Float16*)(wsb + WS_CL);
    float*     ccp  = (float*)(wsb + WS_CC);
    #pragma unroll
    for (int i = 0; i < 4; i++) {
        long row = (long)blockIdx.x * 16 + v * 4 + i;
        float x = w[row * DIM + lane];
        float h = fmaf(x, a, bb);
        float ss = h * h;
        #pragma unroll
        for (int m = 1; m < 64; m <<= 1) ss += __shfl_xor(ss, m);
        float rms = rsqrtf(ss * (1.0f / DIM) + EPS_RMS);
        float c = h * rms;
        cb32[row * DIM + lane] = c;
        _Float16 ch = (_Float16)c;
        chG[row * DIM + lane] = ch;
        clG[row * DIM + lane] = (_Float16)(c - (float)ch);
        float cs = c * c;
        #pragma unroll
        for (int m = 1; m < 64; m <<= 1) cs += __shfl_xor(cs, m);
        if (lane == 0) ccp[row] = -0.5f * cs;   // folded into MFMA C-init
    }
}

// ---- main: 64 rows/block, 4096 codes, f16-split MFMA, 2-phase dbuf pipeline
__global__ __launch_bounds__(256, 2) void k_main(const float* __restrict__ z,
                                                 const char* __restrict__ wsb,
                                                 float* __restrict__ out) {
    // 2 x 32KB code-tile buffers (hi 16KB + lo 16KB each)
    __shared__ __align__(16) unsigned char sm[65536];

    const int tid  = threadIdx.x;
    const int lane = tid & 63;
    const int w    = tid >> 6;
    const int wr   = w >> 1;        // row half
    const int wc   = w & 1;         // code half
    const int l15  = lane & 15;
    const int l4   = lane >> 4;
    const long rowbase = (long)blockIdx.x * 64;

    const _Float16* chG  = (const _Float16*)(wsb + WS_CH);
    const _Float16* clG  = (const _Float16*)(wsb + WS_CL);
    const float*    ccnG = (const float*)(wsb + WS_CC);
    const float*    cb32 = (const float*)(wsb + WS_CB32);

    // staging geometry (pass-invariant): lane fills linear LDS byte B of the tile,
    // sourced from the inverse-swizzled global element
    const int B0    = w * 4096 + lane * 16;
    const int scode = B0 >> 7;
    const int ssp   = (B0 >> 4) & 7;
    const long gsw  = (long)scode * DIM + (long)((ssp ^ (scode & 7)) * 8);

    // ---- issue stage of pass 0 into buf0 immediately (overlaps z prologue)
    #pragma unroll
    for (int i = 0; i < 4; i++) {
        async_copy16(sm + B0 + i * 1024,         chG + gsw + i * 8 * DIM / 8 * 8);
    }
    #pragma unroll
    for (int i = 0; i < 4; i++) {
        async_copy16(sm + 16384 + B0 + i * 1024, clG + gsw + i * 8 * DIM / 8 * 8);
    }
    // note: i*1024 bytes = 8 codes = i*8*DIM f16 elements in global

    // ---- prologue: RMS-norm 64 rows of z, write z_e, split hi/lo into buf1 area
    {
        int r = tid >> 2, seg = tid & 3;
        const float* zrow = z + (rowbase + r) * DIM + seg * 16;
        float vv[16];
        float ss = 0.f;
        #pragma unroll
        for (int i = 0; i < 16; i++) { vv[i] = zrow[i]; ss += vv[i] * vv[i]; }
        ss += __shfl_xor(ss, 1);
        ss += __shfl_xor(ss, 2);
        float rms = rsqrtf(ss * (1.0f / DIM) + EPS_RMS);
        float* oz = out + OUT1 + (rowbase + r) * DIM + seg * 16;
        __align__(16) _Float16 hb[16], lb[16];
        #pragma unroll
        for (int i = 0; i < 16; i++) {
            float x = vv[i] * rms;
            oz[i] = x;
            _Float16 h = (_Float16)x;
            hb[i] = h;
            lb[i] = (_Float16)(x - (float)h);
        }
        unsigned char* zhp = sm + 32768 + r * 128 + seg * 32;
        unsigned char* zlp = sm + 40960 + r * 128 + seg * 32;
        ((f16x8*)zhp)[0] = ((f16x8*)hb)[0];
        ((f16x8*)zhp)[1] = ((f16x8*)hb)[1];
        ((f16x8*)zlp)[0] = ((f16x8*)lb)[0];
        ((f16x8*)zlp)[1] = ((f16x8*)lb)[1];
    }
    __syncthreads();

    // ---- A fragments (z) to registers
    f16x8 ah[2][2], al[2][2];
    #pragma unroll
    for (int s = 0; s < 2; s++)
        #pragma unroll
        for (int c = 0; c < 2; c++) {
            int arow = wr * 32 + s * 16 + l15;
            ah[s][c] = *(const f16x8*)(sm + 32768 + arow * 128 + c * 64 + l4 * 16);
            al[s][c] = *(const f16x8*)(sm + 40960 + arow * 128 + c * 64 + l4 * 16);
        }
    __syncthreads();   // buf1 free for tile staging from here

    // B-fragment LDS offsets (pass-invariant, XOR-swizzled)
    int boff[4][2];
    #pragma unroll
    for (int q = 0; q < 4; q++) {
        int coderow = wc * 64 + q * 16 + l15;
        #pragma unroll
        for (int c = 0; c < 2; c++)
            boff[q][c] = coderow * 128 + ((c * 64 + l4 * 16) ^ ((coderow & 7) << 4));
    }

    float ccv[4];
    #pragma unroll
    for (int q = 0; q < 4; q++)
        ccv[q] = ccnG[wc * 64 + q * 16 + l15];

    float bmax[2][4];
    int   bix[2][4];
    #pragma unroll
    for (int s = 0; s < 2; s++)
        #pragma unroll
        for (int r = 0; r < 4; r++) { bmax[s][r] = -3.4e38f; bix[s][r] = 0; }

    for (int p = 0; p < 32; ++p) {
        // prefetch ccn + stage next tile into the other buffer (overlaps compute)
        float ccn_nx[4];
        if (p + 1 < 32) {
            const float* cn = ccnG + (p + 1) * 128;
            #pragma unroll
            for (int q = 0; q < 4; q++)
                ccn_nx[q] = cn[wc * 64 + q * 16 + l15];
            unsigned char* nb = sm + ((p + 1) & 1) * 32768;
            const _Float16* gh = chG + (long)(p + 1) * 128 * DIM + gsw;
            const _Float16* gl = clG + (long)(p + 1) * 128 * DIM + gsw;
            #pragma unroll
            for (int i = 0; i < 4; i++)
                async_copy16(nb + B0 + i * 1024,         gh + i * 512);
            #pragma unroll
            for (int i = 0; i < 4; i++)
                async_copy16(nb + 16384 + B0 + i * 1024, gl + i * 512);
        }

        const unsigned char* chT = sm + (p & 1) * 32768;
        const unsigned char* clT = chT + 16384;

        #pragma unroll 2
        for (int q = 0; q < 4; q++) {
            f16x8 bh[2], bl[2];
            #pragma unroll
            for (int c = 0; c < 2; c++) {
                bh[c] = *(const f16x8*)(chT + boff[q][c]);
                bl[c] = *(const f16x8*)(clT + boff[q][c]);
            }
            int code = p * 128 + wc * 64 + q * 16 + l15;
            f32x4 ci = {ccv[q], ccv[q], ccv[q], ccv[q]};
            #pragma unroll
            for (int s = 0; s < 2; s++) {
                // two independent 3-deep MFMA chains (k-chunk 0 / 1)
                f32x4 a0 = MFMA16(ah[s][0], bh[0], ci);
                a0 = MFMA16(ah[s][0], bl[0], a0);
                a0 = MFMA16(al[s][0], bh[0], a0);
                f32x4 zz = {0.f, 0.f, 0.f, 0.f};
                f32x4 a1 = MFMA16(ah[s][1], bh[1], zz);
                a1 = MFMA16(ah[s][1], bl[1], a1);
                a1 = MFMA16(al[s][1], bh[1], a1);
                #pragma unroll
                for (int r = 0; r < 4; r++) {
                    float v = a0[r] + a1[r];   // = dot - 0.5*cc : argmax == argmin d2
                    if (v > bmax[s][r]) { bmax[s][r] = v; bix[s][r] = code; }
                }
            }
        }
        __syncthreads();   // drains next-tile staging; closes reads of current buf
        #pragma unroll
        for (int q = 0; q < 4; q++) ccv[q] = ccn_nx[q];
    }

    // ---- argmax reduce: 16 code-lanes, then the 2 code-waves
    float* redd = (float*)sm;          // [64][2]
    int*   redi = (int*)(sm + 512);    // [64][2]
    int*   bidx = (int*)(sm + 1024);   // [64]
    #pragma unroll
    for (int s = 0; s < 2; s++)
        #pragma unroll
        for (int r = 0; r < 4; r++) {
            float d = bmax[s][r];
            int   ix = bix[s][r];
            #pragma unroll
            for (int m = 1; m < 16; m <<= 1) {
                float od = __shfl_xor(d, m);
                int   oi = __shfl_xor(ix, m);
                if (od > d || (od == d && oi < ix)) { d = od; ix = oi; }
            }
            if (l15 == 0) {
                int rowloc = wr * 32 + s * 16 + l4 * 4 + r;
                redd[rowloc * 2 + wc] = d;
                redi[rowloc * 2 + wc] = ix;
            }
        }
    __syncthreads();
    if (tid < 64) {
        float d0 = redd[tid * 2 + 0], d1 = redd[tid * 2 + 1];
        int   i0 = redi[tid * 2 + 0], i1 = redi[tid * 2 + 1];
        int ix = (d1 > d0 || (d1 == d0 && i1 < i0)) ? i1 : i0;
        bidx[tid] = ix;
        out[OUT2 + rowbase + tid] = (float)ix;
    }
    __syncthreads();
    {   // gather cb32[best] -> chunk0 and chunk3
        int r = tid >> 2, seg = tid & 3;
        int ix = bidx[r];
        const float* src = cb32 + (long)ix * DIM + seg * 16;
        float* o0 = out + (rowbase + r) * DIM + seg * 16;
        float* o3 = out + OUT3 + (rowbase + r) * DIM + seg * 16;
        #pragma unroll
        for (int i = 0; i < 16; i++) { float t = src[i]; o0[i] = t; o3[i] = t; }
    }
}

extern "C" void kernel_launch(void* const* d_in, const int* in_sizes, int n_in,
                              void* d_out, int out_size, void* d_ws, size_t ws_size,
                              hipStream_t stream) {
    const float* z   = (const float*)d_in[0];
    const float* w   = (const float*)d_in[1];
    const float* bnw = (const float*)d_in[2];
    const float* bnb = (const float*)d_in[3];
    float* out = (float*)d_out;
    char*  wsb = (char*)d_ws;

    k_bn1 <<<64,  256, 0, stream>>>(w, wsb);
    k_cb  <<<256, 256, 0, stream>>>(w, bnw, bnb, wsb);
    k_main<<<512, 256, 0, stream>>>(z, wsb, out);
}

// Round 4
// 72.463 us; speedup vs baseline: 1.2098x; 1.2098x over previous
//
#include <hip/hip_runtime.h>
#include <math.h>

#define NROWS 32768
#define DIM   64
#define NCODE 4096
#define EPS_RMS 1.1920929e-07f
#define EPS_BN  1e-5f

typedef _Float16 f16x8 __attribute__((ext_vector_type(8)));
typedef float    f32x4 __attribute__((ext_vector_type(4)));

// ws byte layout
#define WS_PS   0                        // partial sums   [64][64] f32
#define WS_PQ   16384                    // partial sumsq  [64][64] f32
#define WS_CC   32768                    // ccn[4096] = -0.5*sum(c^2)
#define WS_CB32 49152                    // cb fp32 [4096][64]
#define WS_CH   (49152 + 1048576)        // cb f16 hi [4096][64]
#define WS_CL   (WS_CH + 524288)         // cb f16 lo [4096][64]

// out float offsets
#define OUT1 ((size_t)NROWS * DIM)           // z_e
#define OUT2 ((size_t)2 * NROWS * DIM)       // q
#define OUT3 (OUT2 + NROWS)                  // z_q

#define MFMA16(a, b, c) __builtin_amdgcn_mfma_f32_16x16x32_f16(a, b, c, 0, 0, 0)

__device__ __forceinline__ void async_copy16(void* lds, const void* g) {
    __builtin_amdgcn_global_load_lds(
        (const __attribute__((address_space(1))) unsigned int*)g,
        (__attribute__((address_space(3))) unsigned int*)lds, 16, 0, 0);
}

__global__ __launch_bounds__(256) void k_bn1(const float* __restrict__ w,
                                             char* __restrict__ wsb) {
    __shared__ float s1[4][64], s2[4][64];
    int lane = threadIdx.x & 63, v = threadIdx.x >> 6;
    long base = (long)blockIdx.x * 64 + v * 16;
    float s = 0.f, sq = 0.f;
    #pragma unroll
    for (int i = 0; i < 16; i++) {
        float x = w[(base + i) * DIM + lane];
        s += x; sq += x * x;
    }
    s1[v][lane] = s; s2[v][lane] = sq;
    __syncthreads();
    if (threadIdx.x < 64) {
        float ts = s1[0][lane] + s1[1][lane] + s1[2][lane] + s1[3][lane];
        float tq = s2[0][lane] + s2[1][lane] + s2[2][lane] + s2[3][lane];
        ((float*)(wsb + WS_PS))[blockIdx.x * 64 + lane] = ts;
        ((float*)(wsb + WS_PQ))[blockIdx.x * 64 + lane] = tq;
    }
}

__global__ __launch_bounds__(256) void k_cb(const float* __restrict__ w,
                                            const float* __restrict__ bnw,
                                            const float* __restrict__ bnb,
                                            char* __restrict__ wsb) {
    __shared__ float s1[4][64], s2[4][64], af[64], bf[64];
    int t = threadIdx.x, lane = t & 63, v = t >> 6;
    const float* ps = (const float*)(wsb + WS_PS);
    const float* pq = (const float*)(wsb + WS_PQ);
    float s = 0.f, sq = 0.f;
    #pragma unroll
    for (int b = 0; b < 16; b++) {
        s  += ps[(v * 16 + b) * 64 + lane];
        sq += pq[(v * 16 + b) * 64 + lane];
    }
    s1[v][lane] = s; s2[v][lane] = sq;
    __syncthreads();
    if (t < 64) {
        float ts = s1[0][lane] + s1[1][lane] + s1[2][lane] + s1[3][lane];
        float tq = s2[0][lane] + s2[1][lane] + s2[2][lane] + s2[3][lane];
        float mean = ts * (1.0f / NCODE);
        float var  = tq * (1.0f / NCODE) - mean * mean;
        float a = rsqrtf(var + EPS_BN) * bnw[lane];
        af[lane] = a;
        bf[lane] = bnb[lane] - mean * a;
    }
    __syncthreads();
    float a = af[lane], bb = bf[lane];
    float*     cb32 = (float*)(wsb + WS_CB32);
    _Float16*  chG  = (_Float16*)(wsb + WS_CH);
    _Float16*  clG  = (_Float16*)(wsb + WS_CL);
    float*     ccp  = (float*)(wsb + WS_CC);
    #pragma unroll
    for (int i = 0; i < 4; i++) {
        long row = (long)blockIdx.x * 16 + v * 4 + i;
        float x = w[row * DIM + lane];
        float h = fmaf(x, a, bb);
        float ss = h * h;
        #pragma unroll
        for (int m = 1; m < 64; m <<= 1) ss += __shfl_xor(ss, m);
        float rms = rsqrtf(ss * (1.0f / DIM) + EPS_RMS);
        float c = h * rms;
        cb32[row * DIM + lane] = c;
        _Float16 ch = (_Float16)c;
        chG[row * DIM + lane] = ch;
        clG[row * DIM + lane] = (_Float16)(c - (float)ch);
        float cs = c * c;
        #pragma unroll
        for (int m = 1; m < 64; m <<= 1) cs += __shfl_xor(cs, m);
        if (lane == 0) ccp[row] = -0.5f * cs;   // folded into MFMA C-init
    }
}

// ---- main: 512 threads / 8 waves, 64 rows/block, 4096 codes, f16-split MFMA
//      waves: wr = w>>2 (row half, 32 rows), wc = w&3 (code quarter, 32 codes/pass)
__global__ __launch_bounds__(512, 4) void k_main(const float* __restrict__ z,
                                                 const char* __restrict__ wsb,
                                                 float* __restrict__ out) {
    // buf0 @0 (hi 16K + lo 16K), buf1 @32768; z prologue overlays buf1
    __shared__ __align__(16) unsigned char sm[65536];

    const int tid  = threadIdx.x;
    const int lane = tid & 63;
    const int w    = tid >> 6;      // 0..7
    const int wr   = w >> 2;        // row half
    const int wc   = w & 3;         // code quarter
    const int l15  = lane & 15;
    const int l4   = lane >> 4;
    const long rowbase = (long)blockIdx.x * 64;

    const _Float16* chG  = (const _Float16*)(wsb + WS_CH);
    const _Float16* clG  = (const _Float16*)(wsb + WS_CL);
    const float*    ccnG = (const float*)(wsb + WS_CC);
    const float*    cb32 = (const float*)(wsb + WS_CB32);

    // staging geometry: per wave 2KB chunks; LDS dest is wave-uniform base
    // (HW adds lane*16); global src is per-lane, inverse-XOR-swizzled
    const int B0    = w * 2048 + lane * 16;        // linear LDS byte (i=0)
    const int scode = B0 >> 7;
    const int ssp   = (B0 >> 4) & 7;
    const long gsw  = (long)scode * DIM + (long)((ssp ^ (scode & 7)) * 8);

    // ---- stage pass 0 into buf0 (overlaps z prologue)
    async_copy16(sm + w * 2048,                chG + gsw);
    async_copy16(sm + w * 2048 + 1024,         chG + gsw + 512);
    async_copy16(sm + 16384 + w * 2048,        clG + gsw);
    async_copy16(sm + 16384 + w * 2048 + 1024, clG + gsw + 512);

    // ---- prologue: RMS-norm 64 rows of z, write z_e, split hi/lo into buf1
    {
        int r = tid >> 3, seg = tid & 7;   // 8 floats per thread
        const float* zrow = z + (rowbase + r) * DIM + seg * 8;
        float vv[8];
        float ss = 0.f;
        #pragma unroll
        for (int i = 0; i < 8; i++) { vv[i] = zrow[i]; ss += vv[i] * vv[i]; }
        ss += __shfl_xor(ss, 1);
        ss += __shfl_xor(ss, 2);
        ss += __shfl_xor(ss, 4);
        float rms = rsqrtf(ss * (1.0f / DIM) + EPS_RMS);
        float* oz = out + OUT1 + (rowbase + r) * DIM + seg * 8;
        __align__(16) _Float16 hb[8], lb[8];
        #pragma unroll
        for (int i = 0; i < 8; i++) {
            float x = vv[i] * rms;
            oz[i] = x;
            _Float16 h = (_Float16)x;
            hb[i] = h;
            lb[i] = (_Float16)(x - (float)h);
        }
        *(f16x8*)(sm + 32768 + r * 128 + seg * 16) = *(f16x8*)hb;
        *(f16x8*)(sm + 40960 + r * 128 + seg * 16) = *(f16x8*)lb;
    }
    __syncthreads();

    // ---- A fragments (z) to registers: 2 row-subtiles x 2 k-chunks, hi+lo
    f16x8 ah[2][2], al[2][2];
    #pragma unroll
    for (int s = 0; s < 2; s++)
        #pragma unroll
        for (int c = 0; c < 2; c++) {
            int arow = wr * 32 + s * 16 + l15;
            ah[s][c] = *(const f16x8*)(sm + 32768 + arow * 128 + c * 64 + l4 * 16);
            al[s][c] = *(const f16x8*)(sm + 40960 + arow * 128 + c * 64 + l4 * 16);
        }
    __syncthreads();   // buf1 free for staging from here

    // B-fragment LDS offsets (pass-invariant, XOR-swizzled)
    int boff[2][2];
    #pragma unroll
    for (int q = 0; q < 2; q++) {
        int coderow = wc * 32 + q * 16 + l15;
        #pragma unroll
        for (int c = 0; c < 2; c++)
            boff[q][c] = coderow * 128 + ((c * 64 + l4 * 16) ^ ((coderow & 7) << 4));
    }
    const int codeoff = wc * 32 + l15;   // + p*128 + q*16

    float ccv[2];
    #pragma unroll
    for (int q = 0; q < 2; q++)
        ccv[q] = ccnG[codeoff + q * 16];

    float bmax[2][4];
    int   bix[2][4];
    #pragma unroll
    for (int s = 0; s < 2; s++)
        #pragma unroll
        for (int r = 0; r < 4; r++) { bmax[s][r] = -3.4e38f; bix[s][r] = 0; }

    #define COMPUTE_PASS(p)                                                        \
    {                                                                              \
        const unsigned char* chT = sm + ((p) & 1) * 32768;                         \
        const unsigned char* clT = chT + 16384;                                    \
        _Pragma("unroll")                                                          \
        for (int q = 0; q < 2; q++) {                                              \
            f16x8 bh[2], bl[2];                                                    \
            _Pragma("unroll")                                                      \
            for (int c = 0; c < 2; c++) {                                          \
                bh[c] = *(const f16x8*)(chT + boff[q][c]);                         \
                bl[c] = *(const f16x8*)(clT + boff[q][c]);                         \
            }                                                                      \
            int code = (p) * 128 + codeoff + q * 16;                               \
            f32x4 acc = {ccv[q], ccv[q], ccv[q], ccv[q]};                          \
            _Pragma("unroll")                                                      \
            for (int s = 0; s < 2; s++) {                                          \
                f32x4 a2 = (s == 0) ? acc : (f32x4){ccv[q], ccv[q], ccv[q], ccv[q]}; \
                a2 = MFMA16(ah[s][0], bh[0], a2);                                  \
                a2 = MFMA16(ah[s][1], bh[1], a2);                                  \
                a2 = MFMA16(ah[s][0], bl[0], a2);                                  \
                a2 = MFMA16(ah[s][1], bl[1], a2);                                  \
                a2 = MFMA16(al[s][0], bh[0], a2);                                  \
                a2 = MFMA16(al[s][1], bh[1], a2);                                  \
                _Pragma("unroll")                                                  \
                for (int r = 0; r < 4; r++) {                                      \
                    if (a2[r] > bmax[s][r]) { bmax[s][r] = a2[r]; bix[s][r] = code; } \
                }                                                                  \
            }                                                                      \
        }                                                                          \
    }

    for (int p = 0; p < 31; ++p) {
        // stage pass p+1 into the other buffer (flies under this pass's compute)
        {
            unsigned char* nb = sm + ((p + 1) & 1) * 32768;
            const _Float16* gh = chG + (long)(p + 1) * (128 * DIM) + gsw;
            const _Float16* gl = clG + (long)(p + 1) * (128 * DIM) + gsw;
            async_copy16(nb + w * 2048,                gh);
            async_copy16(nb + w * 2048 + 1024,         gh + 512);
            async_copy16(nb + 16384 + w * 2048,        gl);
            async_copy16(nb + 16384 + w * 2048 + 1024, gl + 512);
        }
        float ccn_nx0 = ccnG[(p + 1) * 128 + codeoff];
        float ccn_nx1 = ccnG[(p + 1) * 128 + codeoff + 16];

        COMPUTE_PASS(p);

        __syncthreads();   // drains staging; closes reads of current buffer
        ccv[0] = ccn_nx0;
        ccv[1] = ccn_nx1;
    }
    COMPUTE_PASS(31);

    // ---- argmax reduce: 16 code-lanes, then the 4 code-quarter waves
    float* redd = (float*)sm;            // [64][4]
    int*   redi = (int*)(sm + 1024);     // [64][4]
    int*   bidx = (int*)(sm + 2048);     // [64]
    #pragma unroll
    for (int s = 0; s < 2; s++)
        #pragma unroll
        for (int r = 0; r < 4; r++) {
            float d = bmax[s][r];
            int   ix = bix[s][r];
            #pragma unroll
            for (int m = 1; m < 16; m <<= 1) {
                float od = __shfl_xor(d, m);
                int   oi = __shfl_xor(ix, m);
                if (od > d || (od == d && oi < ix)) { d = od; ix = oi; }
            }
            if (l15 == 0) {
                int rowloc = wr * 32 + s * 16 + l4 * 4 + r;
                redd[rowloc * 4 + wc] = d;
                redi[rowloc * 4 + wc] = ix;
            }
        }
    __syncthreads();
    if (tid < 64) {
        float bv = redd[tid * 4];
        int   bi_ = redi[tid * 4];
        #pragma unroll
        for (int j = 1; j < 4; j++) {
            float dj = redd[tid * 4 + j];
            int   ij = redi[tid * 4 + j];
            if (dj > bv || (dj == bv && ij < bi_)) { bv = dj; bi_ = ij; }
        }
        bidx[tid] = bi_;
        out[OUT2 + rowbase + tid] = (float)bi_;
    }
    __syncthreads();
    {   // gather cb32[best] -> chunk0 and chunk3
        int r = tid >> 3, seg = tid & 7;
        int ix = bidx[r];
        const float* src = cb32 + (long)ix * DIM + seg * 8;
        float* o0 = out + (rowbase + r) * DIM + seg * 8;
        float* o3 = out + OUT3 + (rowbase + r) * DIM + seg * 8;
        #pragma unroll
        for (int i = 0; i < 8; i++) { float t = src[i]; o0[i] = t; o3[i] = t; }
    }
}

extern "C" void kernel_launch(void* const* d_in, const int* in_sizes, int n_in,
                              void* d_out, int out_size, void* d_ws, size_t ws_size,
                              hipStream_t stream) {
    const float* z   = (const float*)d_in[0];
    const float* w   = (const float*)d_in[1];
    const float* bnw = (const float*)d_in[2];
    const float* bnb = (const float*)d_in[3];
    float* out = (float*)d_out;
    char*  wsb = (char*)d_ws;

    k_bn1 <<<64,  256, 0, stream>>>(w, wsb);
    k_cb  <<<256, 256, 0, stream>>>(w, bnw, bnb, wsb);
    k_main<<<512, 512, 0, stream>>>(z, wsb, out);
}